// Round 2
// baseline (794.319 us; speedup 1.0000x reference)
//
#include <hip/hip_runtime.h>

typedef unsigned int uint;
typedef unsigned short ushort;

#define U_N 200000
#define M_N 50000
#define E_N 400000

__device__ __forceinline__ float bl(uint u){ return __uint_as_float(u<<16); }
__device__ __forceinline__ float bh(uint u){ return __uint_as_float(u & 0xffff0000u); }
__device__ __forceinline__ float b2f(ushort s){ return __uint_as_float(((uint)s)<<16); }
__device__ __forceinline__ ushort f2b(float f){ uint u=__float_as_uint(f); return (ushort)((u + 0x7fffu + ((u>>16)&1u)) >> 16); }
__device__ __forceinline__ float ldf(const void* p, int f32, size_t i){
  return f32 ? ((const float*)p)[i] : b2f(((const ushort*)p)[i]);
}

// ---- dtype detector: true-bf16 weights (0.1*N(0,1)) never have |v|>=64;
// f32 low halves decode as bf16 with random exponents -> certain trigger.
__global__ void k_detect(const ushort* __restrict__ wl, int n, int* __restrict__ flag){
  __shared__ int s;
  if(threadIdx.x==0) s=0;
  __syncthreads();
  int any=0;
  for(int i=threadIdx.x;i<n;i+=256){ int e=(wl[i]>>7)&0xff; if(e>133) any=1; }
  if(any) atomicOr(&s,1);
  __syncthreads();
  if(threadIdx.x==0) *flag=s;
}

__global__ void k_zero(int* __restrict__ p, int n){ int i=blockIdx.x*256+threadIdx.x; if(i<n) p[i]=0; }

__global__ void k_count(const int* __restrict__ dst, int* __restrict__ deg, int n){
  int e=blockIdx.x*256+threadIdx.x; if(e<n) atomicAdd(&deg[dst[e]],1);
}

__global__ __launch_bounds__(1024) void k_scan1(const int* __restrict__ cnt, int* __restrict__ rowptr,
                                                int* __restrict__ bsum, int n){
  __shared__ int wsum[16];
  int t=threadIdx.x; int b=blockIdx.x;
  int i=b*1024+t;
  int v=(i<n)?cnt[i]:0;
  int lane=t&63, w=t>>6;
  int x=v;
  #pragma unroll
  for(int off=1;off<64;off<<=1){ int y=__shfl_up(x,off,64); if(lane>=off) x+=y; }
  if(lane==63) wsum[w]=x;
  __syncthreads();
  if(t<16){
    int ws=wsum[t];
    #pragma unroll
    for(int off=1;off<16;off<<=1){ int y=__shfl_up(ws,off,64); if(t>=off) ws+=y; }
    wsum[t]=ws;
  }
  __syncthreads();
  int incl=x + (w>0? wsum[w-1]:0);
  if(i<n) rowptr[i+1]=incl;
  if(t==1023) bsum[b]=incl;
  if(b==0&&t==0) rowptr[0]=0;
}

__global__ __launch_bounds__(1024) void k_scan2(int* __restrict__ bsum, int nb){
  __shared__ int sm[1024];
  int t=threadIdx.x;
  int v=(t<nb)?bsum[t]:0;
  sm[t]=v;
  __syncthreads();
  for(int off=1;off<1024;off<<=1){
    int a=(t>=off)?sm[t-off]:0;
    __syncthreads();
    sm[t]+=a;
    __syncthreads();
  }
  if(t<nb) bsum[t]=sm[t]-v;   // exclusive
}

__global__ __launch_bounds__(1024) void k_scan3(int* __restrict__ rowptr, const int* __restrict__ bsum, int n){
  int i=blockIdx.x*1024+threadIdx.x;
  if(i<n) rowptr[i+1]+=bsum[blockIdx.x];
}

__global__ void k_scatter(const int* __restrict__ dst, const int* __restrict__ src,
                          const int* __restrict__ rowptr, int* __restrict__ cur,
                          int* __restrict__ nbr, int n){
  int e=blockIdx.x*256+threadIdx.x;
  if(e<n){ int d=dst[e]; int p=rowptr[d]+atomicAdd(&cur[d],1); nbr[p]=src[e]; }
}

// V[k*4+h] = sum_c W[k][h*32+c] * att[h][c]  (collapses dst-side transform to a GEMV)
__global__ void k_makeV(const void* __restrict__ W, const void* __restrict__ att,
                        float* __restrict__ V, int K, const int* __restrict__ dflag){
  int f=*dflag;
  int t=blockIdx.x*512+threadIdx.x;
  if(t>=K*4) return;
  int k=t>>2, h=t&3;
  float s=0.f;
  for(int c=0;c<32;c++) s += ldf(W,f,(size_t)k*128 + h*32 + c)*ldf(att,f,h*32+c);
  V[t]=s;
}

// a[n*4+h] = sum_k X[n][k] * V[k*4+h]
__global__ void k_ad(const void* __restrict__ X, int xraw, const float* __restrict__ V,
                     float* __restrict__ a, int N, int K, const int* __restrict__ dflag){
  int f=(*dflag)&xraw;
  int gid=blockIdx.x*256+threadIdx.x;
  if(gid>=N*4) return;
  int n=gid>>2, h=gid&3;
  float s=0.f;
  if(f){
    const float* xr=(const float*)X+(size_t)n*K;
    for(int k=0;k<K;k++) s=fmaf(xr[k],V[k*4+h],s);
  }else{
    const ushort* xr=(const ushort*)X+(size_t)n*K;
    for(int k=0;k<K;k+=2){
      uint xp=*(const uint*)&xr[k];
      s = fmaf(bl(xp), V[k*4+h], s);
      s = fmaf(bh(xp), V[(k+1)*4+h], s);
    }
  }
  a[gid]=s;
}

// hs[N,128] = X[N,K] @ W[K,128]  (f32 acc, bf16 out), plus a_s epilogue.
// In-place safe (hs may alias X): each block stages its own 64 rows in LDS
// before computing, and only writes back those same rows.
template<int K>
__global__ __launch_bounds__(256) void k_gemm(const void* __restrict__ X, int xraw,
        const void* __restrict__ W, const void* __restrict__ att,
        ushort* __restrict__ hs, float* __restrict__ a_s, int N, const int* __restrict__ dflag)
{
  const int f=*dflag;
  const int xf=f&xraw;
  constexpr int XS = K + 8;
  __shared__ __align__(16) ushort Wl[K*128];
  __shared__ __align__(16) ushort Xl[64*XS];
  const int t = threadIdx.x;
  const int row0 = blockIdx.x*64;
  #pragma unroll
  for(int i=0;i<(K*128)/2048;i++){
    int j=(i*256+t)*8;
    uint4 o;
    if(f){
      const float* wp=(const float*)W + j;
      float4 lo=*(const float4*)wp, hi=*(const float4*)(wp+4);
      o.x=(uint)f2b(lo.x)|((uint)f2b(lo.y)<<16);
      o.y=(uint)f2b(lo.z)|((uint)f2b(lo.w)<<16);
      o.z=(uint)f2b(hi.x)|((uint)f2b(hi.y)<<16);
      o.w=(uint)f2b(hi.z)|((uint)f2b(hi.w)<<16);
    } else o=*(const uint4*)((const ushort*)W + j);
    *(uint4*)&Wl[j]=o;
  }
  #pragma unroll
  for(int i=0;i<(64*K)/2048;i++){
    int j=(i*256+t)*8;
    int r=j/K, c=j%K;
    uint4 o;
    if(row0+r<N){
      if(xf){
        const float* xp=(const float*)X + (size_t)(row0+r)*K + c;
        float4 lo=*(const float4*)xp, hi=*(const float4*)(xp+4);
        o.x=(uint)f2b(lo.x)|((uint)f2b(lo.y)<<16);
        o.y=(uint)f2b(lo.z)|((uint)f2b(lo.w)<<16);
        o.z=(uint)f2b(hi.x)|((uint)f2b(hi.y)<<16);
        o.w=(uint)f2b(hi.z)|((uint)f2b(hi.w)<<16);
      } else o=*(const uint4*)((const ushort*)X + (size_t)(row0+r)*K + c);
    } else { o.x=0u;o.y=0u;o.z=0u;o.w=0u; }
    *(uint4*)&Xl[r*XS+c]=o;
  }
  __syncthreads();
  const int cg = t&15, rg = t>>4;
  float acc[4][8];
  #pragma unroll
  for(int i=0;i<4;i++){
    #pragma unroll
    for(int j=0;j<8;j++) acc[i][j]=0.f;
  }
  for(int k=0;k<K;k+=4){
    float xv[4][4];
    #pragma unroll
    for(int i=0;i<4;i++){
      uint2 xp = *(const uint2*)&Xl[(rg*4+i)*XS + k];
      xv[i][0]=bl(xp.x); xv[i][1]=bh(xp.x); xv[i][2]=bl(xp.y); xv[i][3]=bh(xp.y);
    }
    #pragma unroll
    for(int kk=0;kk<4;kk++){
      uint4 wq = *(const uint4*)&Wl[(k+kk)*128 + cg*8];
      float wv[8];
      wv[0]=bl(wq.x); wv[1]=bh(wq.x); wv[2]=bl(wq.y); wv[3]=bh(wq.y);
      wv[4]=bl(wq.z); wv[5]=bh(wq.z); wv[6]=bl(wq.w); wv[7]=bh(wq.w);
      #pragma unroll
      for(int i=0;i<4;i++){
        float x=xv[i][kk];
        #pragma unroll
        for(int j=0;j<8;j++) acc[i][j] = fmaf(x, wv[j], acc[i][j]);
      }
    }
  }
  float attv[8];
  #pragma unroll
  for(int j=0;j<8;j++) attv[j]=ldf(att,f,cg*8+j);
  #pragma unroll
  for(int i=0;i<4;i++){
    int r = row0 + rg*4 + i;
    float p=0.f;
    #pragma unroll
    for(int j=0;j<8;j++) p = fmaf(acc[i][j], attv[j], p);
    p += __shfl_xor(p,1);
    p += __shfl_xor(p,2);
    if(r<N){
      uint4 o;
      o.x = (uint)f2b(acc[i][0]) | ((uint)f2b(acc[i][1])<<16);
      o.y = (uint)f2b(acc[i][2]) | ((uint)f2b(acc[i][3])<<16);
      o.z = (uint)f2b(acc[i][4]) | ((uint)f2b(acc[i][5])<<16);
      o.w = (uint)f2b(acc[i][6]) | ((uint)f2b(acc[i][7])<<16);
      *(uint4*)&hs[(size_t)r*128 + cg*8] = o;
      if((t&3)==0) a_s[(size_t)r*4 + (cg>>2)] = p;
    }
  }
}

// One wave per dst node: online segment-softmax + weighted aggregation over CSR.
__global__ __launch_bounds__(64) void k_aggr(const int* __restrict__ rowptr, const int* __restrict__ nbr,
    const float* __restrict__ a_s, const float* __restrict__ a_d, const ushort* __restrict__ hs,
    const void* __restrict__ bias, void* __restrict__ outbase, long long eoff, int osel,
    int Ndst, const int* __restrict__ dflag)
{
  int fl=*dflag;
  int of=fl&osel;
  int d = blockIdx.x; int lane = threadIdx.x;
  int beg = rowptr[d], end = rowptr[d+1];
  float4 ad4 = *(const float4*)(a_d + (size_t)d*4);
  bool lo = lane<32;
  float ad0 = lo? ad4.x : ad4.y;
  float ad1 = lo? ad4.z : ad4.w;
  float m0=-__builtin_inff(), m1=-__builtin_inff();
  float s0=0.f,s1=0.f,acc0=0.f,acc1=0.f;
  for(int i=beg;i<end;++i){
    int sn = nbr[i];
    float4 as4 = *(const float4*)(a_s + (size_t)sn*4);
    float al0 = (lo? as4.x:as4.y) + ad0; al0 = fmaxf(al0, 0.2f*al0);
    float al1 = (lo? as4.z:as4.w) + ad1; al1 = fmaxf(al1, 0.2f*al1);
    float nm0 = fmaxf(m0, al0), nm1 = fmaxf(m1, al1);
    float sc0 = __expf(m0-nm0), sc1 = __expf(m1-nm1);
    float p0 = __expf(al0-nm0), p1 = __expf(al1-nm1);
    m0=nm0; m1=nm1;
    s0 = s0*sc0 + p0; s1 = s1*sc1 + p1;
    const ushort* hr = hs + (size_t)sn*128;
    float h0 = b2f(hr[lane]), h1 = b2f(hr[64+lane]);
    acc0 = fmaf(p0, h0, acc0*sc0);
    acc1 = fmaf(p1, h1, acc1*sc1);
  }
  float r0 = acc0/(s0+1e-16f) + ldf(bias,fl,lane);
  float r1 = acc1/(s1+1e-16f) + ldf(bias,fl,64+lane);
  r0 = fmaxf(r0, 0.01f*r0); r1 = fmaxf(r1, 0.01f*r1);
  size_t o0=(size_t)eoff + (size_t)d*128 + lane;
  if(of){
    float* ob=(float*)outbase; ob[o0]=r0; ob[o0+64]=r1;
  }else{
    ushort* ob=(ushort*)outbase; ob[o0]=f2b(r0); ob[o0+64]=f2b(r1);
  }
}

// logits[M,64] = m2[M,128] @ w_lin[128,64] + b_lin  (m2 read in OUTPUT dtype)
__global__ __launch_bounds__(256) void k_logits(void* __restrict__ outbase, long long m2eoff,
      const void* __restrict__ wlin, const void* __restrict__ blin, int Nrows, const int* __restrict__ dflag){
  int f=*dflag;
  __shared__ float Wl[128*64];
  int t=threadIdx.x;
  for(int i=0;i<32;i++){ int j=i*256+t; Wl[j]=ldf(wlin,f,j); }
  __syncthreads();
  int o = t&63;
  int rb = blockIdx.x*32 + (t>>6)*8;
  float bv = ldf(blin,f,o);
  for(int rr=0; rr<8; rr++){
    int n = rb+rr;
    if(n>=Nrows) break;
    size_t re=(size_t)m2eoff+(size_t)n*128;
    float s=0.f;
    if(f){
      const float* mr=(const float*)outbase + re;
      for(int k=0;k<128;k+=4){
        float4 v=*(const float4*)(mr+k);
        s=fmaf(v.x,Wl[k*64+o],s); s=fmaf(v.y,Wl[(k+1)*64+o],s);
        s=fmaf(v.z,Wl[(k+2)*64+o],s); s=fmaf(v.w,Wl[(k+3)*64+o],s);
      }
    }else{
      const ushort* mr=(const ushort*)outbase + re;
      for(int k=0;k<128;k+=2){
        uint xp=*(const uint*)&mr[k];
        s = fmaf(bl(xp), Wl[k*64+o], s);
        s = fmaf(bh(xp), Wl[(k+1)*64+o], s);
      }
    }
    s+=bv;
    if(f) ((float*)outbase)[(size_t)n*64+o]=s;
    else ((ushort*)outbase)[(size_t)n*64+o]=f2b(s);
  }
}

extern "C" void kernel_launch(void* const* d_in, const int* in_sizes, int n_in,
                              void* d_out, int out_size, void* d_ws, size_t ws_size,
                              hipStream_t stream) {
  const int U=U_N, M=M_N, E=E_N;
  const void* embU   =d_in[0];
  const void* embM   =d_in[1];
  const void* w0umS  =d_in[2];
  const void* w0umD  =d_in[3];
  const void* a0umS  =d_in[4];
  const void* a0umD  =d_in[5];
  const void* b0um   =d_in[6];
  const void* w0muS  =d_in[7];
  const void* w0muD  =d_in[8];
  const void* a0muS  =d_in[9];
  const void* a0muD  =d_in[10];
  const void* b0mu   =d_in[11];
  const void* w1um   =d_in[12];
  const void* a1umS  =d_in[13];
  const void* a1umD  =d_in[14];
  const void* b1um   =d_in[15];
  const void* w1mu   =d_in[16];
  const void* a1muS  =d_in[17];
  const void* a1muD  =d_in[18];
  const void* b1mu   =d_in[19];
  const void* wlin   =d_in[20];
  const void* blin   =d_in[21];
  const int* src_um  =(const int*)d_in[24];
  const int* dst_um  =(const int*)d_in[25];
  const int* src_mu  =(const int*)d_in[26];
  const int* dst_mu  =(const int*)d_in[27];

  char* w=(char*)d_ws;
  size_t off=0;
  auto take=[&](size_t bytes)->char*{ char* p=w+off; off=(off+bytes+255)&~(size_t)255; return p; };
  ushort* bigbuf=(ushort*)take((size_t)U*128*2);   // conv1 hs, then u1 (conv3 runs in-place here)
  ushort* m1    =(ushort*)take((size_t)M*128*2);   // conv4 runs in-place here
  ushort* hsM   =(ushort*)take((size_t)M*128*2);   // conv2 hs
  float*  a_s   =(float*) take((size_t)U*4*4);
  float*  a_dU  =(float*) take((size_t)U*4*4);
  float*  a_dM  =(float*) take((size_t)M*4*4);
  float*  vd    =(float*) take(4096);
  int* rp_um    =(int*)   take((size_t)(M+1)*4);
  int* nbr_um   =(int*)   take((size_t)E*4);
  int* rp_mu    =(int*)   take((size_t)(U+1)*4);
  int* nbr_mu   =(int*)   take((size_t)E*4);
  int* dflag    =(int*)   take(256);
  // CSR-build temporaries alias m1 (m1 is written only later, by conv1's aggr)
  int* tmp  =(int*)m1;
  int* bsum =(int*)((char*)m1 + (4<<20));
  (void)ws_size; (void)in_sizes; (void)n_in; (void)out_size;

  const int nbM=(M+1023)/1024, nbU=(U+1023)/1024;
  const int gE=(E+255)/256;
  const int gU64=U/64, gM64=(M+63)/64;
  const int gU4=(U*4+255)/256, gM4=(M*4+255)/256;

  // ---- dtype detect ----
  k_detect<<<1,256,0,stream>>>((const ushort*)wlin, 8192, dflag);

  // ---- CSR by dst (reused by both layers) ----
  k_zero<<<(M+255)/256,256,0,stream>>>(tmp,M);
  k_count<<<gE,256,0,stream>>>(dst_um,tmp,E);
  k_scan1<<<nbM,1024,0,stream>>>(tmp,rp_um,bsum,M);
  k_scan2<<<1,1024,0,stream>>>(bsum,nbM);
  k_scan3<<<nbM,1024,0,stream>>>(rp_um,bsum,M);
  k_zero<<<(M+255)/256,256,0,stream>>>(tmp,M);
  k_scatter<<<gE,256,0,stream>>>(dst_um,src_um,rp_um,tmp,nbr_um,E);

  k_zero<<<(U+255)/256,256,0,stream>>>(tmp,U);
  k_count<<<gE,256,0,stream>>>(dst_mu,tmp,E);
  k_scan1<<<nbU,1024,0,stream>>>(tmp,rp_mu,bsum,U);
  k_scan2<<<1,1024,0,stream>>>(bsum,nbU);
  k_scan3<<<nbU,1024,0,stream>>>(rp_mu,bsum,U);
  k_zero<<<(U+255)/256,256,0,stream>>>(tmp,U);
  k_scatter<<<gE,256,0,stream>>>(dst_mu,src_mu,rp_mu,tmp,nbr_mu,E);

  // ---- conv1: user->movie, layer 0 -> m1 (bf16 internal) ----
  k_makeV<<<1,512,0,stream>>>(w0umD,a0umD,vd,64,dflag);
  k_gemm<64><<<gU64,256,0,stream>>>(embU,1,w0umS,a0umS,bigbuf,a_s,U,dflag);
  k_ad<<<gM4,256,0,stream>>>(embM,1,vd,a_dM,M,64,dflag);
  k_aggr<<<M,64,0,stream>>>(rp_um,nbr_um,a_s,a_dM,bigbuf,b0um,m1,0,0,M,dflag);

  // ---- conv2: movie->user, layer 0 -> u1 (= bigbuf; conv1 hs dead) ----
  k_makeV<<<1,512,0,stream>>>(w0muD,a0muD,vd,64,dflag);
  k_gemm<64><<<gM64,256,0,stream>>>(embM,1,w0muS,a0muS,hsM,a_s,M,dflag);
  k_ad<<<gU4,256,0,stream>>>(embU,1,vd,a_dU,U,64,dflag);
  k_aggr<<<U,64,0,stream>>>(rp_mu,nbr_mu,a_s,a_dU,hsM,b0mu,bigbuf,0,0,U,dflag);

  // ---- precompute layer-1 a_d BEFORE in-place gemms clobber u1/m1 ----
  k_makeV<<<1,512,0,stream>>>(w1mu,a1muD,vd,128,dflag);
  k_ad<<<gU4,256,0,stream>>>(bigbuf,0,vd,a_dU,U,128,dflag);   // conv4's a_d (from u1)
  k_makeV<<<1,512,0,stream>>>(w1um,a1umD,vd,128,dflag);
  k_ad<<<gM4,256,0,stream>>>(m1,0,vd,a_dM,M,128,dflag);       // conv3's a_d (from m1)

  // ---- conv3: user->movie, layer 1 -> m2 (in-place gemm on u1) ----
  k_gemm<128><<<gU64,256,0,stream>>>(bigbuf,0,w1um,a1umS,bigbuf,a_s,U,dflag);
  k_aggr<<<M,64,0,stream>>>(rp_um,nbr_um,a_s,a_dM,bigbuf,b1um,d_out,(long long)M*64,1,M,dflag);

  // ---- conv4: movie->user, layer 1 -> u2 (in-place gemm on m1) ----
  k_gemm<128><<<gM64,256,0,stream>>>(m1,0,w1mu,a1muS,m1,a_s,M,dflag);
  k_aggr<<<U,64,0,stream>>>(rp_mu,nbr_mu,a_s,a_dU,m1,b1mu,d_out,(long long)M*192,1,U,dflag);

  // ---- final linear ----
  k_logits<<<(M+31)/32,256,0,stream>>>(d_out,(long long)M*64,wlin,blin,M,dflag);
}

// Round 3
// 608.906 us; speedup vs baseline: 1.3045x; 1.3045x over previous
//
#include <hip/hip_runtime.h>

typedef unsigned int uint;
typedef unsigned short ushort;
typedef __attribute__((ext_vector_type(8))) short bf16x8;
typedef __attribute__((ext_vector_type(4))) float f32x4;

#define U_N 200000
#define M_N 50000
#define E_N 400000

__device__ __forceinline__ float bl(uint u){ return __uint_as_float(u<<16); }
__device__ __forceinline__ float bh(uint u){ return __uint_as_float(u & 0xffff0000u); }
__device__ __forceinline__ float b2f(ushort s){ return __uint_as_float(((uint)s)<<16); }
__device__ __forceinline__ ushort f2b(float f){ uint u=__float_as_uint(f); return (ushort)((u + 0x7fffu + ((u>>16)&1u)) >> 16); }
__device__ __forceinline__ float ldf(const void* p, int f32, size_t i){
  return f32 ? ((const float*)p)[i] : b2f(((const ushort*)p)[i]);
}

// ---- dtype detector: true-bf16 weights (0.1*N(0,1)) never have |v|>=64 ----
__global__ void k_detect(const ushort* __restrict__ wl, int n, int* __restrict__ flag){
  __shared__ int s;
  if(threadIdx.x==0) s=0;
  __syncthreads();
  int any=0;
  for(int i=threadIdx.x;i<n;i+=256){ int e=(wl[i]>>7)&0xff; if(e>133) any=1; }
  if(any) atomicOr(&s,1);
  __syncthreads();
  if(threadIdx.x==0) *flag=s;
}

__global__ void k_zero(int* __restrict__ p, int n){ int i=blockIdx.x*256+threadIdx.x; if(i<n) p[i]=0; }

__global__ void k_count(const int* __restrict__ dst, int* __restrict__ deg, int n){
  int e=blockIdx.x*256+threadIdx.x; if(e<n) atomicAdd(&deg[dst[e]],1);
}

__global__ __launch_bounds__(1024) void k_scan1(const int* __restrict__ cnt, int* __restrict__ rowptr,
                                                int* __restrict__ bsum, int n){
  __shared__ int wsum[16];
  int t=threadIdx.x; int b=blockIdx.x;
  int i=b*1024+t;
  int v=(i<n)?cnt[i]:0;
  int lane=t&63, w=t>>6;
  int x=v;
  #pragma unroll
  for(int off=1;off<64;off<<=1){ int y=__shfl_up(x,off,64); if(lane>=off) x+=y; }
  if(lane==63) wsum[w]=x;
  __syncthreads();
  if(t<16){
    int ws=wsum[t];
    #pragma unroll
    for(int off=1;off<16;off<<=1){ int y=__shfl_up(ws,off,64); if(t>=off) ws+=y; }
    wsum[t]=ws;
  }
  __syncthreads();
  int incl=x + (w>0? wsum[w-1]:0);
  if(i<n) rowptr[i+1]=incl;
  if(t==1023) bsum[b]=incl;
  if(b==0&&t==0) rowptr[0]=0;
}

__global__ __launch_bounds__(1024) void k_scan2(int* __restrict__ bsum, int nb){
  __shared__ int sm[1024];
  int t=threadIdx.x;
  int v=(t<nb)?bsum[t]:0;
  sm[t]=v;
  __syncthreads();
  for(int off=1;off<1024;off<<=1){
    int a=(t>=off)?sm[t-off]:0;
    __syncthreads();
    sm[t]+=a;
    __syncthreads();
  }
  if(t<nb) bsum[t]=sm[t]-v;   // exclusive
}

__global__ __launch_bounds__(1024) void k_scan3(int* __restrict__ rowptr, const int* __restrict__ bsum, int n){
  int i=blockIdx.x*1024+threadIdx.x;
  if(i<n) rowptr[i+1]+=bsum[blockIdx.x];
}

__global__ void k_scatter(const int* __restrict__ dst, const int* __restrict__ src,
                          const int* __restrict__ rowptr, int* __restrict__ cur,
                          int* __restrict__ nbr, int n){
  int e=blockIdx.x*256+threadIdx.x;
  if(e<n){ int d=dst[e]; int p=rowptr[d]+atomicAdd(&cur[d],1); nbr[p]=src[e]; }
}

// W[K][128] -> Wt[128][K] bf16 (handles f32 input via flag)
__global__ void k_transW(const void* __restrict__ W, ushort* __restrict__ Wt, int K,
                         const int* __restrict__ dflag){
  int f=*dflag;
  int gid=blockIdx.x*256+threadIdx.x;
  if(gid>=128*K) return;
  int c=gid/K, k=gid-c*K;
  Wt[gid]=f2b(ldf(W,f,(size_t)k*128+c));
}

// Vt[16][K] bf16: rows 0-3 Vs_hi(h), 4-7 Vs_lo, 8-11 Vd_hi, 12-15 Vd_lo
// Vs[k][h] = sum_c Wsrc[k][h*32+c]*attS[h][c];  Vd from (Wdst, attD)
__global__ void k_makeV2(const void* __restrict__ Wsrc, const void* __restrict__ attS,
                         const void* __restrict__ Wdst, const void* __restrict__ attD,
                         ushort* __restrict__ Vt, int K, const int* __restrict__ dflag){
  int f=*dflag;
  int t=blockIdx.x*256+threadIdx.x;
  if(t>=4*K) return;
  int h=t/K, k=t-h*K;
  float vs=0.f, vd=0.f;
  for(int c=0;c<32;c++){
    vs += ldf(Wsrc,f,(size_t)k*128+h*32+c)*ldf(attS,f,h*32+c);
    vd += ldf(Wdst,f,(size_t)k*128+h*32+c)*ldf(attD,f,h*32+c);
  }
  ushort vsh=f2b(vs); Vt[h*K+k]=vsh;      Vt[(h+4)*K+k]=f2b(vs-b2f(vsh));
  ushort vdh=f2b(vd); Vt[(h+8)*K+k]=vdh;  Vt[(h+12)*K+k]=f2b(vd-b2f(vdh));
}

// hs[N,128] = X[N,K] @ W[K,128] via MFMA; epilogue a_s = X@Vs, a_dO = X@Vd
// (one extra MFMA per K-step with packed 16-col V operand).
// In-place safe: block stages its own 64 rows before writing them back.
template<int K>
__global__ __launch_bounds__(256) void k_gemm(const void* __restrict__ X, int xraw,
        const ushort* __restrict__ WtG, const ushort* __restrict__ VtG,
        ushort* __restrict__ hs, float* __restrict__ a_s, float* __restrict__ a_dO,
        int N, const int* __restrict__ dflag)
{
  const int xf=(*dflag)&xraw;
  constexpr int XS = K + 8;
  __shared__ __align__(16) ushort Wl[128*XS];
  __shared__ __align__(16) ushort Xl[64*XS];
  __shared__ __align__(16) ushort Vl[16*XS];
  const int t = threadIdx.x;
  const int row0 = blockIdx.x*64;
  #pragma unroll
  for(int i=0;i<(128*K)/2048;i++){
    int j=(i*256+t)*8; int r=j/K, c=j-r*K;
    *(uint4*)&Wl[r*XS+c] = *(const uint4*)&WtG[j];
  }
  { int j=t*8; if(j<16*K){ int r=j/K, c=j-r*K; *(uint4*)&Vl[r*XS+c]=*(const uint4*)&VtG[j]; } }
  #pragma unroll
  for(int i=0;i<(64*K)/2048;i++){
    int j=(i*256+t)*8; int r=j/K, c=j-r*K;
    uint4 o;
    if(row0+r<N){
      if(xf){
        const float* xp=(const float*)X + (size_t)(row0+r)*K + c;
        float4 lo=*(const float4*)xp, hi=*(const float4*)(xp+4);
        o.x=(uint)f2b(lo.x)|((uint)f2b(lo.y)<<16);
        o.y=(uint)f2b(lo.z)|((uint)f2b(lo.w)<<16);
        o.z=(uint)f2b(hi.x)|((uint)f2b(hi.y)<<16);
        o.w=(uint)f2b(hi.z)|((uint)f2b(hi.w)<<16);
      } else o=*(const uint4*)((const ushort*)X + (size_t)(row0+r)*K + c);
    } else { o.x=0u;o.y=0u;o.z=0u;o.w=0u; }
    *(uint4*)&Xl[r*XS+c]=o;
  }
  __syncthreads();
  const int l=t&63, w=t>>6;
  const ushort* xb=&Xl[(w*16+(l&15))*XS + (l>>4)*8];
  const ushort* wb=&Wl[(l&15)*XS + (l>>4)*8];
  const ushort* vb=&Vl[(l&15)*XS + (l>>4)*8];
  f32x4 accC[8]; f32x4 accV;
  #pragma unroll
  for(int c=0;c<8;c++){ accC[c][0]=0.f;accC[c][1]=0.f;accC[c][2]=0.f;accC[c][3]=0.f; }
  accV[0]=0.f;accV[1]=0.f;accV[2]=0.f;accV[3]=0.f;
  #pragma unroll
  for(int s=0;s<K/32;s++){
    bf16x8 a=*(const bf16x8*)(xb+s*32);
    accV=__builtin_amdgcn_mfma_f32_16x16x32_bf16(a,*(const bf16x8*)(vb+s*32),accV,0,0,0);
    #pragma unroll
    for(int c=0;c<8;c++)
      accC[c]=__builtin_amdgcn_mfma_f32_16x16x32_bf16(a,*(const bf16x8*)(wb+c*16*XS+s*32),accC[c],0,0,0);
  }
  const int q=l&15;
  #pragma unroll
  for(int i=0;i<4;i++){
    int r=row0 + w*16 + (l>>4)*4 + i;
    float av=accV[i]+__shfl_xor(accV[i],4);
    if(r<N){
      if(q<4) a_s[(size_t)r*4+q]=av;
      else if(q>=8&&q<12) a_dO[(size_t)r*4+(q-8)]=av;
      #pragma unroll
      for(int c=0;c<8;c++) hs[(size_t)r*128 + c*16 + q]=f2b(accC[c][i]);
    }
  }
}

// 4 dst nodes per 256-thread block (one wave each): online segment-softmax + aggregate.
__global__ __launch_bounds__(256) void k_aggr(const int* __restrict__ rowptr, const int* __restrict__ nbr,
    const float* __restrict__ a_s, const float* __restrict__ a_d, const ushort* __restrict__ hs,
    const void* __restrict__ bias, void* __restrict__ outbase, long long eoff, int osel,
    int Ndst, const int* __restrict__ dflag)
{
  int fl=*dflag;
  int of=fl&osel;
  int d = blockIdx.x*4 + (threadIdx.x>>6);
  int lane = threadIdx.x&63;
  if(d>=Ndst) return;
  int beg = rowptr[d], end = rowptr[d+1];
  float4 ad4 = *(const float4*)(a_d + (size_t)d*4);
  bool lo = lane<32;
  float ad0 = lo? ad4.x : ad4.y;
  float ad1 = lo? ad4.z : ad4.w;
  float m0=-__builtin_inff(), m1=-__builtin_inff();
  float s0=0.f,s1=0.f,acc0=0.f,acc1=0.f;
  for(int i=beg;i<end;++i){
    int sn = nbr[i];
    float4 as4 = *(const float4*)(a_s + (size_t)sn*4);
    float al0 = (lo? as4.x:as4.y) + ad0; al0 = fmaxf(al0, 0.2f*al0);
    float al1 = (lo? as4.z:as4.w) + ad1; al1 = fmaxf(al1, 0.2f*al1);
    float nm0 = fmaxf(m0, al0), nm1 = fmaxf(m1, al1);
    float sc0 = __expf(m0-nm0), sc1 = __expf(m1-nm1);
    float p0 = __expf(al0-nm0), p1 = __expf(al1-nm1);
    m0=nm0; m1=nm1;
    s0 = s0*sc0 + p0; s1 = s1*sc1 + p1;
    const ushort* hr = hs + (size_t)sn*128;
    float h0 = b2f(hr[lane]), h1 = b2f(hr[64+lane]);
    acc0 = fmaf(p0, h0, acc0*sc0);
    acc1 = fmaf(p1, h1, acc1*sc1);
  }
  float r0 = acc0/(s0+1e-16f) + ldf(bias,fl,lane);
  float r1 = acc1/(s1+1e-16f) + ldf(bias,fl,64+lane);
  r0 = fmaxf(r0, 0.01f*r0); r1 = fmaxf(r1, 0.01f*r1);
  size_t o0=(size_t)eoff + (size_t)d*128 + lane;
  if(of){
    float* ob=(float*)outbase; ob[o0]=r0; ob[o0+64]=r1;
  }else{
    ushort* ob=(ushort*)outbase; ob[o0]=f2b(r0); ob[o0+64]=f2b(r1);
  }
}

// logits[M,64] = m2[M,128] @ w_lin[128,64] + b_lin  (m2 read in OUTPUT dtype)
__global__ __launch_bounds__(256) void k_logits(void* __restrict__ outbase, long long m2eoff,
      const void* __restrict__ wlin, const void* __restrict__ blin, int Nrows, const int* __restrict__ dflag){
  int f=*dflag;
  __shared__ float Wl[128*64];
  int t=threadIdx.x;
  for(int i=0;i<32;i++){ int j=i*256+t; Wl[j]=ldf(wlin,f,j); }
  __syncthreads();
  int o = t&63;
  int rb = blockIdx.x*32 + (t>>6)*8;
  float bv = ldf(blin,f,o);
  for(int rr=0; rr<8; rr++){
    int n = rb+rr;
    if(n>=Nrows) break;
    size_t re=(size_t)m2eoff+(size_t)n*128;
    float s=0.f;
    if(f){
      const float* mr=(const float*)outbase + re;
      for(int k=0;k<128;k+=4){
        float4 v=*(const float4*)(mr+k);
        s=fmaf(v.x,Wl[k*64+o],s); s=fmaf(v.y,Wl[(k+1)*64+o],s);
        s=fmaf(v.z,Wl[(k+2)*64+o],s); s=fmaf(v.w,Wl[(k+3)*64+o],s);
      }
    }else{
      const ushort* mr=(const ushort*)outbase + re;
      for(int k=0;k<128;k+=2){
        uint xp=*(const uint*)&mr[k];
        s = fmaf(bl(xp), Wl[k*64+o], s);
        s = fmaf(bh(xp), Wl[(k+1)*64+o], s);
      }
    }
    s+=bv;
    if(f) ((float*)outbase)[(size_t)n*64+o]=s;
    else ((ushort*)outbase)[(size_t)n*64+o]=f2b(s);
  }
}

extern "C" void kernel_launch(void* const* d_in, const int* in_sizes, int n_in,
                              void* d_out, int out_size, void* d_ws, size_t ws_size,
                              hipStream_t stream) {
  const int U=U_N, M=M_N, E=E_N;
  const void* embU   =d_in[0];
  const void* embM   =d_in[1];
  const void* w0umS  =d_in[2];
  const void* w0umD  =d_in[3];
  const void* a0umS  =d_in[4];
  const void* a0umD  =d_in[5];
  const void* b0um   =d_in[6];
  const void* w0muS  =d_in[7];
  const void* w0muD  =d_in[8];
  const void* a0muS  =d_in[9];
  const void* a0muD  =d_in[10];
  const void* b0mu   =d_in[11];
  const void* w1um   =d_in[12];
  const void* a1umS  =d_in[13];
  const void* a1umD  =d_in[14];
  const void* b1um   =d_in[15];
  const void* w1mu   =d_in[16];
  const void* a1muS  =d_in[17];
  const void* a1muD  =d_in[18];
  const void* b1mu   =d_in[19];
  const void* wlin   =d_in[20];
  const void* blin   =d_in[21];
  const int* src_um  =(const int*)d_in[24];
  const int* dst_um  =(const int*)d_in[25];
  const int* src_mu  =(const int*)d_in[26];
  const int* dst_mu  =(const int*)d_in[27];

  char* w=(char*)d_ws;
  size_t off=0;
  auto take=[&](size_t bytes)->char*{ char* p=w+off; off=(off+bytes+255)&~(size_t)255; return p; };
  ushort* bigbuf=(ushort*)take((size_t)U*128*2);   // conv1 hs -> u1 (conv3 in-place)
  ushort* m1    =(ushort*)take((size_t)M*128*2);   // conv4 in-place
  ushort* hsM   =(ushort*)take((size_t)M*128*2);   // conv2 hs
  float*  a_sU  =(float*) take((size_t)U*4*4);
  float*  a_sM  =(float*) take((size_t)M*4*4);
  float*  a_dU  =(float*) take((size_t)U*4*4);
  float*  a_dM  =(float*) take((size_t)M*4*4);
  ushort* Wt    =(ushort*)take(128*128*2);
  ushort* Vt    =(ushort*)take(16*128*2);
  int* rp_um    =(int*)   take((size_t)(M+1)*4);
  int* nbr_um   =(int*)   take((size_t)E*4);
  int* rp_mu    =(int*)   take((size_t)(U+1)*4);
  int* nbr_mu   =(int*)   take((size_t)E*4);
  int* dflag    =(int*)   take(256);
  // CSR-build temporaries alias m1 (first written later, by aggr1)
  int* tmp  =(int*)m1;
  int* bsum =(int*)((char*)m1 + (4<<20));
  (void)ws_size; (void)in_sizes; (void)n_in; (void)out_size;

  const int nbM=(M+1023)/1024, nbU=(U+1023)/1024;
  const int gE=(E+255)/256;
  const int gU64=U/64, gM64=(M+63)/64;

  // ---- dtype detect ----
  k_detect<<<1,256,0,stream>>>((const ushort*)wlin, 8192, dflag);

  // ---- CSR by dst (reused by both layers) ----
  k_zero<<<(M+255)/256,256,0,stream>>>(tmp,M);
  k_count<<<gE,256,0,stream>>>(dst_um,tmp,E);
  k_scan1<<<nbM,1024,0,stream>>>(tmp,rp_um,bsum,M);
  k_scan2<<<1,1024,0,stream>>>(bsum,nbM);
  k_scan3<<<nbM,1024,0,stream>>>(rp_um,bsum,M);
  k_zero<<<(M+255)/256,256,0,stream>>>(tmp,M);
  k_scatter<<<gE,256,0,stream>>>(dst_um,src_um,rp_um,tmp,nbr_um,E);

  k_zero<<<(U+255)/256,256,0,stream>>>(tmp,U);
  k_count<<<gE,256,0,stream>>>(dst_mu,tmp,E);
  k_scan1<<<nbU,1024,0,stream>>>(tmp,rp_mu,bsum,U);
  k_scan2<<<1,1024,0,stream>>>(bsum,nbU);
  k_scan3<<<nbU,1024,0,stream>>>(rp_mu,bsum,U);
  k_zero<<<(U+255)/256,256,0,stream>>>(tmp,U);
  k_scatter<<<gE,256,0,stream>>>(dst_mu,src_mu,rp_mu,tmp,nbr_mu,E);

  // ---- layer 0 GEMMs (fused a_s + cross-conv a_d) ----
  k_transW<<<(128*64+255)/256,256,0,stream>>>(w0umS,Wt,64,dflag);
  k_makeV2<<<1,256,0,stream>>>(w0umS,a0umS,w0muD,a0muD,Vt,64,dflag);
  k_gemm<64><<<gU64,256,0,stream>>>(embU,1,Wt,Vt,bigbuf,a_sU,a_dU,U,dflag);

  k_transW<<<(128*64+255)/256,256,0,stream>>>(w0muS,Wt,64,dflag);
  k_makeV2<<<1,256,0,stream>>>(w0muS,a0muS,w0umD,a0umD,Vt,64,dflag);
  k_gemm<64><<<gM64,256,0,stream>>>(embM,1,Wt,Vt,hsM,a_sM,a_dM,M,dflag);

  // ---- layer 0 aggregation ----
  k_aggr<<<(M+3)/4,256,0,stream>>>(rp_um,nbr_um,a_sU,a_dM,bigbuf,b0um,m1,0,0,M,dflag);
  k_aggr<<<(U+3)/4,256,0,stream>>>(rp_mu,nbr_mu,a_sM,a_dU,hsM,b0mu,bigbuf,0,0,U,dflag);

  // ---- layer 1 GEMMs (both before aggrs; each computes the other's a_d) ----
  k_transW<<<(128*128+255)/256,256,0,stream>>>(w1um,Wt,128,dflag);
  k_makeV2<<<2,256,0,stream>>>(w1um,a1umS,w1mu,a1muD,Vt,128,dflag);
  k_gemm<128><<<gU64,256,0,stream>>>(bigbuf,0,Wt,Vt,bigbuf,a_sU,a_dU,U,dflag);

  k_transW<<<(128*128+255)/256,256,0,stream>>>(w1mu,Wt,128,dflag);
  k_makeV2<<<2,256,0,stream>>>(w1mu,a1muS,w1um,a1umD,Vt,128,dflag);
  k_gemm<128><<<gM64,256,0,stream>>>(m1,0,Wt,Vt,m1,a_sM,a_dM,M,dflag);

  // ---- layer 1 aggregation -> d_out ----
  k_aggr<<<(M+3)/4,256,0,stream>>>(rp_um,nbr_um,a_sU,a_dM,bigbuf,b1um,d_out,(long long)M*64,1,M,dflag);
  k_aggr<<<(U+3)/4,256,0,stream>>>(rp_mu,nbr_mu,a_sM,a_dU,m1,b1mu,d_out,(long long)M*192,1,U,dflag);

  // ---- final linear ----
  k_logits<<<(M+31)/32,256,0,stream>>>(d_out,(long long)M*64,wlin,blin,M,dflag);
}

// Round 4
// 489.850 us; speedup vs baseline: 1.6216x; 1.2430x over previous
//
#include <hip/hip_runtime.h>

typedef unsigned int uint;
typedef unsigned short ushort;
typedef __attribute__((ext_vector_type(8))) short bf16x8;
typedef __attribute__((ext_vector_type(4))) float f32x4;

#define U_N 200000
#define M_N 50000
#define E_N 400000

__device__ __forceinline__ float bl(uint u){ return __uint_as_float(u<<16); }
__device__ __forceinline__ float bh(uint u){ return __uint_as_float(u & 0xffff0000u); }
__device__ __forceinline__ float b2f(ushort s){ return __uint_as_float(((uint)s)<<16); }
__device__ __forceinline__ ushort f2b(float f){ uint u=__float_as_uint(f); return (ushort)((u + 0x7fffu + ((u>>16)&1u)) >> 16); }
__device__ __forceinline__ float ldf(const void* p, int f32, size_t i){
  return f32 ? ((const float*)p)[i] : b2f(((const ushort*)p)[i]);
}

// ---- dtype detector: true-bf16 weights (0.1*N(0,1)) never have |v|>=64 ----
__global__ void k_detect(const ushort* __restrict__ wl, int n, int* __restrict__ flag){
  __shared__ int s;
  if(threadIdx.x==0) s=0;
  __syncthreads();
  int any=0;
  for(int i=threadIdx.x;i<n;i+=256){ int e=(wl[i]>>7)&0xff; if(e>133) any=1; }
  if(any) atomicOr(&s,1);
  __syncthreads();
  if(threadIdx.x==0) *flag=s;
}

// ---- all weight prep in one dispatch: Wt (transpose->bf16) + Vt (packed a_s/a_d GEMV cols) ----
struct PrepJob { const void* Ws; const void* attS; const void* Wd; const void* attD;
                 ushort* Wt; ushort* Vt; int K; };

__global__ __launch_bounds__(256) void k_prep(PrepJob p0, PrepJob p1, PrepJob p2, PrepJob p3,
                                              const int* __restrict__ dflag){
  PrepJob P = blockIdx.y==0?p0 : blockIdx.y==1?p1 : blockIdx.y==2?p2 : p3;
  int f=*dflag;
  int gid=blockIdx.x*256+threadIdx.x;
  int K=P.K;
  if(gid<128*K){
    int c=gid/K, k=gid-c*K;
    P.Wt[gid]=f2b(ldf(P.Ws,f,(size_t)k*128+c));
  }
  if(gid<4*K){
    int h=gid/K, k=gid-h*K;
    float vs=0.f, vd=0.f;
    for(int c=0;c<32;c++){
      vs += ldf(P.Ws,f,(size_t)k*128+h*32+c)*ldf(P.attS,f,h*32+c);
      vd += ldf(P.Wd,f,(size_t)k*128+h*32+c)*ldf(P.attD,f,h*32+c);
    }
    ushort vsh=f2b(vs); P.Vt[h*K+k]=vsh;      P.Vt[(h+4)*K+k]=f2b(vs-b2f(vsh));
    ushort vdh=f2b(vd); P.Vt[(h+8)*K+k]=vdh;  P.Vt[(h+12)*K+k]=f2b(vd-b2f(vdh));
  }
}

// ---- CSR build, both graphs per dispatch ----
__global__ void k_zero2(int* __restrict__ a, int na, int* __restrict__ b, int nb){
  int i=blockIdx.x*256+threadIdx.x;
  if(i<na) a[i]=0; else if(i<na+nb) b[i-na]=0;
}

__global__ void k_count2(const int* __restrict__ dA, int* __restrict__ cA,
                         const int* __restrict__ dB, int* __restrict__ cB, int E){
  int e=blockIdx.x*256+threadIdx.x;
  if(e<E) atomicAdd(&cA[dA[e]],1);
  else if(e<2*E) atomicAdd(&cB[dB[e-E]],1);
}

__global__ __launch_bounds__(1024) void k_scan1f(const int* __restrict__ cA, int* __restrict__ rA, int* __restrict__ bA, int nA, int nbA,
                                                 const int* __restrict__ cB, int* __restrict__ rB, int* __restrict__ bB, int nB){
  __shared__ int wsum[16];
  int b=blockIdx.x;
  const int* cnt; int* rp; int* bs; int n; int bb;
  if(b<nbA){ cnt=cA; rp=rA; bs=bA; n=nA; bb=b; }
  else     { cnt=cB; rp=rB; bs=bB; n=nB; bb=b-nbA; }
  int t=threadIdx.x;
  int i=bb*1024+t;
  int v=(i<n)?cnt[i]:0;
  int lane=t&63, w=t>>6;
  int x=v;
  #pragma unroll
  for(int off=1;off<64;off<<=1){ int y=__shfl_up(x,off,64); if(lane>=off) x+=y; }
  if(lane==63) wsum[w]=x;
  __syncthreads();
  if(t<16){
    int ws=wsum[t];
    #pragma unroll
    for(int off=1;off<16;off<<=1){ int y=__shfl_up(ws,off,64); if(t>=off) ws+=y; }
    wsum[t]=ws;
  }
  __syncthreads();
  int incl=x + (w>0? wsum[w-1]:0);
  if(i<n) rp[i+1]=incl;
  if(t==1023) bs[bb]=incl;
  if(bb==0&&t==0) rp[0]=0;
}

__device__ void scan_excl(int* bsum, int nb, int* sm){
  int t=threadIdx.x;
  int v=(t<nb)?bsum[t]:0;
  sm[t]=v;
  __syncthreads();
  for(int off=1;off<1024;off<<=1){
    int a=(t>=off)?sm[t-off]:0;
    __syncthreads();
    sm[t]+=a;
    __syncthreads();
  }
  if(t<nb) bsum[t]=sm[t]-v;
}

__global__ __launch_bounds__(1024) void k_scan2f(int* __restrict__ bA, int nbA, int* __restrict__ bB, int nbB){
  __shared__ int sm[1024];
  scan_excl(bA,nbA,sm);
  __syncthreads();
  scan_excl(bB,nbB,sm);
}

__global__ __launch_bounds__(1024) void k_scan3f(int* __restrict__ rA, int* __restrict__ cA, const int* __restrict__ bA, int nA, int nbA,
                                                 int* __restrict__ rB, int* __restrict__ cB, const int* __restrict__ bB, int nB){
  int b=blockIdx.x;
  int* rp; int* cur; const int* bs; int n; int bb;
  if(b<nbA){ rp=rA; cur=cA; bs=bA; n=nA; bb=b; }
  else     { rp=rB; cur=cB; bs=bB; n=nB; bb=b-nbA; }
  int i=bb*1024+threadIdx.x;
  if(i<n){
    int v=rp[i+1]+bs[bb];
    rp[i+1]=v; cur[i+1]=v;
    if(i==0) cur[0]=0;
  }
}

__global__ void k_scatter2(const int* __restrict__ dA, const int* __restrict__ sA, int* __restrict__ cA, int* __restrict__ nA,
                           const int* __restrict__ dB, const int* __restrict__ sB, int* __restrict__ cB, int* __restrict__ nB, int E){
  int e=blockIdx.x*256+threadIdx.x;
  if(e<E){ int d=dA[e]; nA[atomicAdd(&cA[d],1)]=sA[e]; }
  else if(e<2*E){ int ee=e-E; int d=dB[ee]; nB[atomicAdd(&cB[d],1)]=sB[ee]; }
}

// ---- fused-pair MFMA GEMM: hs = X@W + a_s/a_d epilogue; in-place safe ----
struct GemmJob { const void* X; int xraw; const ushort* Wt; const ushort* Vt;
                 ushort* hs; float* a_s; float* a_d; int N; };

template<int K>
__global__ __launch_bounds__(256) void k_gemm2(GemmJob j0, GemmJob j1, int split,
                                               const int* __restrict__ dflag)
{
  const GemmJob J = (blockIdx.x<(uint)split)? j0 : j1;
  const int blk = (blockIdx.x<(uint)split)? blockIdx.x : blockIdx.x-split;
  const int xf=(*dflag)&J.xraw;
  constexpr int XS = K + 8;
  __shared__ __align__(16) ushort Wl[128*XS];
  __shared__ __align__(16) ushort Xl[64*XS];
  __shared__ __align__(16) ushort Vl[16*XS];
  const int t = threadIdx.x;
  const int row0 = blk*64;
  #pragma unroll
  for(int i=0;i<(128*K)/2048;i++){
    int j=(i*256+t)*8; int r=j/K, c=j-r*K;
    *(uint4*)&Wl[r*XS+c] = *(const uint4*)&J.Wt[j];
  }
  { int j=t*8; if(j<16*K){ int r=j/K, c=j-r*K; *(uint4*)&Vl[r*XS+c]=*(const uint4*)&J.Vt[j]; } }
  #pragma unroll
  for(int i=0;i<(64*K)/2048;i++){
    int j=(i*256+t)*8; int r=j/K, c=j-r*K;
    uint4 o;
    if(row0+r<J.N){
      if(xf){
        const float* xp=(const float*)J.X + (size_t)(row0+r)*K + c;
        float4 lo=*(const float4*)xp, hi=*(const float4*)(xp+4);
        o.x=(uint)f2b(lo.x)|((uint)f2b(lo.y)<<16);
        o.y=(uint)f2b(lo.z)|((uint)f2b(lo.w)<<16);
        o.z=(uint)f2b(hi.x)|((uint)f2b(hi.y)<<16);
        o.w=(uint)f2b(hi.z)|((uint)f2b(hi.w)<<16);
      } else o=*(const uint4*)((const ushort*)J.X + (size_t)(row0+r)*K + c);
    } else { o.x=0u;o.y=0u;o.z=0u;o.w=0u; }
    *(uint4*)&Xl[r*XS+c]=o;
  }
  __syncthreads();
  const int l=t&63, w=t>>6;
  const ushort* xb=&Xl[(w*16+(l&15))*XS + (l>>4)*8];
  const ushort* wb=&Wl[(l&15)*XS + (l>>4)*8];
  const ushort* vb=&Vl[(l&15)*XS + (l>>4)*8];
  f32x4 accC[8]; f32x4 accV;
  #pragma unroll
  for(int c=0;c<8;c++){ accC[c][0]=0.f;accC[c][1]=0.f;accC[c][2]=0.f;accC[c][3]=0.f; }
  accV[0]=0.f;accV[1]=0.f;accV[2]=0.f;accV[3]=0.f;
  #pragma unroll
  for(int s=0;s<K/32;s++){
    bf16x8 a=*(const bf16x8*)(xb+s*32);
    accV=__builtin_amdgcn_mfma_f32_16x16x32_bf16(a,*(const bf16x8*)(vb+s*32),accV,0,0,0);
    #pragma unroll
    for(int c=0;c<8;c++)
      accC[c]=__builtin_amdgcn_mfma_f32_16x16x32_bf16(a,*(const bf16x8*)(wb+c*16*XS+s*32),accC[c],0,0,0);
  }
  const int q=l&15;
  #pragma unroll
  for(int i=0;i<4;i++){
    int r=row0 + w*16 + (l>>4)*4 + i;
    float av=accV[i]+__shfl_xor(accV[i],4);
    if(r<J.N){
      if(q<4) J.a_s[(size_t)r*4+q]=av;
      else if(q>=8&&q<12) J.a_d[(size_t)r*4+(q-8)]=av;
      #pragma unroll
      for(int c=0;c<8;c++) J.hs[(size_t)r*128 + c*16 + q]=f2b(accC[c][i]);
    }
  }
}

// ---- aggregation: lane owns feature pair {2l, 2l+1} (same head) ----
struct AggrJob { const int* rp; const int* nbr; const float* a_s; const float* a_d;
                 const ushort* hs; const void* bias; void* out; long long eoff;
                 int Ndst; int osel; };

__global__ __launch_bounds__(256) void k_aggr2(AggrJob j0, AggrJob j1, int split,
                                               const int* __restrict__ dflag)
{
  const int fl=*dflag;
  const int b=blockIdx.x;
  const AggrJob J = (b<split)? j0 : j1;
  const int base = (b<split)? b : b-split;
  const int d = base*4 + (threadIdx.x>>6);
  if(d>=J.Ndst) return;
  const int lane = threadIdx.x&63;
  const int h = lane>>4;
  const int f0 = lane*2;
  const int beg=J.rp[d], end=J.rp[d+1];
  const float ad = J.a_d[d*4+h];
  float m=-__builtin_inff(), s=0.f, acc0=0.f, acc1=0.f;
  int i=beg;
  int sn=0; float as=0.f; uint hp=0u;
  if(i<end){
    sn=J.nbr[i];
    as=J.a_s[sn*4+h];
    hp=*(const uint*)(J.hs + (size_t)sn*128 + f0);
  }
  while(i<end){
    int i2=i+1;
    int sn2=0; float as2=0.f; uint hp2=0u;
    if(i2<end){
      sn2=J.nbr[i2];
      as2=J.a_s[sn2*4+h];
      hp2=*(const uint*)(J.hs + (size_t)sn2*128 + f0);
    }
    float al = as+ad; al = fmaxf(al, 0.2f*al);
    float nm = fmaxf(m, al);
    float sc = __expf(m-nm);
    float p  = __expf(al-nm);
    m=nm;
    s = fmaf(s, sc, p);
    acc0 = fmaf(p, bl(hp), acc0*sc);
    acc1 = fmaf(p, bh(hp), acc1*sc);
    i=i2; sn=sn2; as=as2; hp=hp2;
  }
  float inv = 1.f/(s+1e-16f);
  float b0v, b1v;
  if(fl){ float2 bp=*(const float2*)((const float*)J.bias+f0); b0v=bp.x; b1v=bp.y; }
  else  { uint bp=*(const uint*)((const ushort*)J.bias+f0); b0v=bl(bp); b1v=bh(bp); }
  float r0 = fmaf(acc0,inv,b0v); r0 = fmaxf(r0, 0.01f*r0);
  float r1 = fmaf(acc1,inv,b1v); r1 = fmaxf(r1, 0.01f*r1);
  if(fl & J.osel){
    float* ob=(float*)J.out + (size_t)J.eoff + (size_t)d*128 + f0;
    float2 o; o.x=r0; o.y=r1;
    *(float2*)ob = o;
  }else{
    ushort* ob=(ushort*)J.out + (size_t)J.eoff + (size_t)d*128 + f0;
    *(uint*)ob = (uint)f2b(r0) | ((uint)f2b(r1)<<16);
  }
}

// logits[M,64] = m2[M,128] @ w_lin[128,64] + b_lin  (m2 read in OUTPUT dtype)
__global__ __launch_bounds__(256) void k_logits(void* __restrict__ outbase, long long m2eoff,
      const void* __restrict__ wlin, const void* __restrict__ blin, int Nrows, const int* __restrict__ dflag){
  int f=*dflag;
  __shared__ float Wl[128*64];
  int t=threadIdx.x;
  for(int i=0;i<32;i++){ int j=i*256+t; Wl[j]=ldf(wlin,f,j); }
  __syncthreads();
  int o = t&63;
  int rb = blockIdx.x*32 + (t>>6)*8;
  float bv = ldf(blin,f,o);
  for(int rr=0; rr<8; rr++){
    int n = rb+rr;
    if(n>=Nrows) break;
    size_t re=(size_t)m2eoff+(size_t)n*128;
    float s=0.f;
    if(f){
      const float* mr=(const float*)outbase + re;
      for(int k=0;k<128;k+=4){
        float4 v=*(const float4*)(mr+k);
        s=fmaf(v.x,Wl[k*64+o],s); s=fmaf(v.y,Wl[(k+1)*64+o],s);
        s=fmaf(v.z,Wl[(k+2)*64+o],s); s=fmaf(v.w,Wl[(k+3)*64+o],s);
      }
    }else{
      const ushort* mr=(const ushort*)outbase + re;
      for(int k=0;k<128;k+=2){
        uint xp=*(const uint*)&mr[k];
        s = fmaf(bl(xp), Wl[k*64+o], s);
        s = fmaf(bh(xp), Wl[(k+1)*64+o], s);
      }
    }
    s+=bv;
    if(f) ((float*)outbase)[(size_t)n*64+o]=s;
    else ((ushort*)outbase)[(size_t)n*64+o]=f2b(s);
  }
}

extern "C" void kernel_launch(void* const* d_in, const int* in_sizes, int n_in,
                              void* d_out, int out_size, void* d_ws, size_t ws_size,
                              hipStream_t stream) {
  const int U=U_N, M=M_N, E=E_N;
  const void* embU   =d_in[0];
  const void* embM   =d_in[1];
  const void* w0umS  =d_in[2];
  const void* w0umD  =d_in[3];
  const void* a0umS  =d_in[4];
  const void* a0umD  =d_in[5];
  const void* b0um   =d_in[6];
  const void* w0muS  =d_in[7];
  const void* w0muD  =d_in[8];
  const void* a0muS  =d_in[9];
  const void* a0muD  =d_in[10];
  const void* b0mu   =d_in[11];
  const void* w1um   =d_in[12];
  const void* a1umS  =d_in[13];
  const void* a1umD  =d_in[14];
  const void* b1um   =d_in[15];
  const void* w1mu   =d_in[16];
  const void* a1muS  =d_in[17];
  const void* a1muD  =d_in[18];
  const void* b1mu   =d_in[19];
  const void* wlin   =d_in[20];
  const void* blin   =d_in[21];
  const int* src_um  =(const int*)d_in[24];
  const int* dst_um  =(const int*)d_in[25];
  const int* src_mu  =(const int*)d_in[26];
  const int* dst_mu  =(const int*)d_in[27];

  char* w=(char*)d_ws;
  size_t off=0;
  auto take=[&](size_t bytes)->char*{ char* p=w+off; off=(off+bytes+255)&~(size_t)255; return p; };
  ushort* bigbuf=(ushort*)take((size_t)U*128*2);   // hsU (layer0), then hsU' (layer1)
  ushort* m1    =(ushort*)take((size_t)M*128*2);   // m1; conv4 gemm in-place
  ushort* hsM   =(ushort*)take((size_t)M*128*2);   // conv2/conv? movie hs
  float*  a_sU  =(float*) take((size_t)U*4*4);
  float*  a_sM  =(float*) take((size_t)M*4*4);
  float*  a_dU  =(float*) take((size_t)U*4*4);
  float*  a_dM  =(float*) take((size_t)M*4*4);
  ushort* Wt0   =(ushort*)take(128*128*2);
  ushort* Wt1   =(ushort*)take(128*128*2);
  ushort* Wt2   =(ushort*)take(128*128*2);
  ushort* Wt3   =(ushort*)take(128*128*2);
  ushort* Vt0   =(ushort*)take(16*128*2);
  ushort* Vt1   =(ushort*)take(16*128*2);
  ushort* Vt2   =(ushort*)take(16*128*2);
  ushort* Vt3   =(ushort*)take(16*128*2);
  int* rp_um    =(int*)   take((size_t)(M+1)*4);
  int* curM     =(int*)   take((size_t)(M+1)*4);
  int* rp_mu    =(int*)   take((size_t)(U+1)*4);
  int* curU     =(int*)   take((size_t)(U+1)*4);
  int* nbr_um   =(int*)   take((size_t)E*4);
  int* nbr_mu   =(int*)   take((size_t)E*4);
  int* bsumM    =(int*)   take(1024*4);
  int* bsumU    =(int*)   take(1024*4);
  int* dflag    =(int*)   take(256);
  (void)ws_size; (void)in_sizes; (void)n_in; (void)out_size;

  // u1 lives in d_out's u2 slot (dead by the time u2 is written)
  ushort* u1 = (ushort*)d_out + (size_t)M*192;

  const int nbM=(M+1023)/1024, nbU=(U+1023)/1024;
  const int gE=(E+255)/256;
  const int gU64=U/64, gM64=(M+63)/64;
  const int spA=(M+3)/4, gA=spA+(U+3)/4;

  // 1. dtype detect
  k_detect<<<1,256,0,stream>>>((const ushort*)wlin, 8192, dflag);

  // 2. all weight prep
  {
    PrepJob p0={w0umS,a0umS,w0muD,a0muD,Wt0,Vt0,64};
    PrepJob p1={w0muS,a0muS,w0umD,a0umD,Wt1,Vt1,64};
    PrepJob p2={w1um,a1umS,w1mu,a1muD,Wt2,Vt2,128};
    PrepJob p3={w1mu,a1muS,w1um,a1umD,Wt3,Vt3,128};
    k_prep<<<dim3(64,4),256,0,stream>>>(p0,p1,p2,p3,dflag);
  }

  // 3-8. CSR build, both graphs
  k_zero2<<<(M+U+2+255)/256,256,0,stream>>>(curM,M+1,curU,U+1);
  k_count2<<<2*gE,256,0,stream>>>(dst_um,curM,dst_mu,curU,E);
  k_scan1f<<<nbM+nbU,1024,0,stream>>>(curM,rp_um,bsumM,M,nbM, curU,rp_mu,bsumU,U);
  k_scan2f<<<1,1024,0,stream>>>(bsumM,nbM,bsumU,nbU);
  k_scan3f<<<nbM+nbU,1024,0,stream>>>(rp_um,curM,bsumM,M,nbM, rp_mu,curU,bsumU,U);
  k_scatter2<<<2*gE,256,0,stream>>>(dst_um,src_um,curM,nbr_um, dst_mu,src_mu,curU,nbr_mu, E);

  // 9. layer-0 GEMMs (fused)
  {
    GemmJob g0={embU,1,Wt0,Vt0,bigbuf,a_sU,a_dU,U};
    GemmJob g1={embM,1,Wt1,Vt1,hsM,a_sM,a_dM,M};
    k_gemm2<64><<<gU64+gM64,256,0,stream>>>(g0,g1,gU64,dflag);
  }
  // 10. layer-0 aggregation (fused): m1 and u1(@d_out slot)
  {
    AggrJob a0={rp_um,nbr_um,a_sU,a_dM,bigbuf,b0um,m1,0,M,0};
    AggrJob a1={rp_mu,nbr_mu,a_sM,a_dU,hsM,b0mu,d_out,(long long)M*192,U,0};
    k_aggr2<<<gA,256,0,stream>>>(a0,a1,spA,dflag);
  }
  // 11. layer-1 GEMMs (fused): conv3 reads u1 -> bigbuf; conv4 in-place on m1
  {
    GemmJob g0={u1,0,Wt2,Vt2,bigbuf,a_sU,a_dU,U};
    GemmJob g1={m1,0,Wt3,Vt3,m1,a_sM,a_dM,M};
    k_gemm2<128><<<gU64+gM64,256,0,stream>>>(g0,g1,gU64,dflag);
  }
  // 12. layer-1 aggregation (fused) -> d_out m2, u2
  {
    AggrJob a0={rp_um,nbr_um,a_sU,a_dM,bigbuf,b1um,d_out,(long long)M*64,M,1};
    AggrJob a1={rp_mu,nbr_mu,a_sM,a_dU,m1,b1mu,d_out,(long long)M*192,U,1};
    k_aggr2<<<gA,256,0,stream>>>(a0,a1,spA,dflag);
  }
  // 13. final linear
  k_logits<<<(M+31)/32,256,0,stream>>>(d_out,(long long)M*64,wlin,blin,M,dflag);
}